// Round 2
// baseline (436.169 us; speedup 1.0000x reference)
//
#include <hip/hip_runtime.h>

// Problem constants (B=8, C=128, H=128, W=256, disp in [-4,4])
#define CC   128
#define HH   128
#define WW   256
#define BB   8
#define HWS  (HH * WW)        // 32768
#define TH   16               // tile rows per block
#define TW   32               // tile cols per block
#define SROWS (TH + 8)        // 24
#define SCOLS (TW + 8)        // 40
#define STILE (SROWS * SCOLS) // 960
#define NTHR 384              // 3 dy-groups x (16 rows x 8 x-chunks)
#define CPI  2                // channels per iteration (per barrier)
#define STG  ((CPI * STILE) / NTHR)  // 5 staged floats per thread per iter

typedef float f4 __attribute__((ext_vector_type(4)));

__global__ __launch_bounds__(NTHR, 3)
void corr_kernel(const float* __restrict__ first,
                 const float* __restrict__ second,
                 float* __restrict__ out)
{
    // double-buffered, 2 channels per buffer: 2*2*960*4 = 15360 B
    __shared__ float s_lds[2 * CPI * STILE];

    const int tid = threadIdx.x;
    const int g   = tid >> 7;          // dy-group 0..2 (dy = 3g-4 .. 3g-2)
    const int p   = tid & 127;
    const int r   = p >> 3;            // local row 0..15
    const int xq  = p & 7;             // x-chunk 0..7
    const int x0  = xq << 2;

    const int bx = blockIdx.x * TW;
    const int by = blockIdx.y * TH;
    const int b  = blockIdx.z;

    const int y  = by + r;
    const int xg = bx + x0;

    // ---- staging map: 5 elements per thread per iteration (2 channels x 960)
    int  goff[STG];     // per-2ch-group offset (incl. ch*HWS), 0 if invalid
    int  lidx[STG];     // LDS index within a buffer
    bool val[STG];
    #pragma unroll
    for (int k = 0; k < STG; ++k) {
        const int i   = tid + k * NTHR;       // 0..1919
        const int ch  = i / STILE;            // 0 or 1
        const int idx = i - ch * STILE;
        const int sr  = idx / SCOLS;
        const int sc  = idx - sr * SCOLS;
        const int ys  = by - 4 + sr;
        const int xs  = bx - 4 + sc;
        val[k]  = ((unsigned)ys < HH) && ((unsigned)xs < WW);
        goff[k] = val[k] ? (ch * HWS + ys * WW + xs) : 0;
        lidx[k] = i;
    }

    const float* sbase = second + (long)b * CC * HWS;

    // ---- accumulators: 3 dy-rows x 9 dx x 4 pixels
    float acc[3][9][4];
    #pragma unroll
    for (int a = 0; a < 3; ++a)
        #pragma unroll
        for (int d = 0; d < 9; ++d)
            #pragma unroll
            for (int q = 0; q < 4; ++q)
                acc[a][d][q] = 0.0f;

    // ---- prologue: stage channels 0,1 into buffer 0
    #pragma unroll
    for (int k = 0; k < STG; ++k) {
        float t = val[k] ? sbase[goff[k]] : 0.0f;
        s_lds[lidx[k]] = t;
    }
    __syncthreads();

    const float* fptr = first + ((long)(b * CC) * HH + y) * WW + xg;

    int cur = 0;
    const int NIT = CC / CPI;   // 64
    for (int it = 0; it < NIT; ++it) {
        // issue next-iteration staging loads EARLY
        float t[STG];
        const bool more = (it + 1 < NIT);
        if (more) {
            const float* sb = sbase + (it + 1) * (CPI * HWS);
            #pragma unroll
            for (int k = 0; k < STG; ++k)
                t[k] = val[k] ? sb[goff[k]] : 0.0f;
        }

        // first: both channels' pixels, coalesced b128
        f4 fv0 = *(const f4*)fptr;
        f4 fv1 = *(const f4*)(fptr + HWS);
        fptr += CPI * HWS;

        // compute 2 channels from current buffer
        #pragma unroll
        for (int cc = 0; cc < CPI; ++cc) {
            const float* sb_lds = &s_lds[cur * (CPI * STILE) + cc * STILE];
            const f4 fv = (cc == 0) ? fv0 : fv1;
            #pragma unroll
            for (int r3 = 0; r3 < 3; ++r3) {
                const int srow = r + g * 3 + r3;   // = r + (dy+4)
                const f4* wp = (const f4*)&sb_lds[srow * SCOLS + x0];
                f4 wa = wp[0];
                f4 wb = wp[1];
                f4 wc = wp[2];
                float w[12];
                w[0] = wa[0]; w[1]  = wa[1]; w[2]  = wa[2]; w[3]  = wa[3];
                w[4] = wb[0]; w[5]  = wb[1]; w[6]  = wb[2]; w[7]  = wb[3];
                w[8] = wc[0]; w[9]  = wc[1]; w[10] = wc[2]; w[11] = wc[3];
                #pragma unroll
                for (int dxi = 0; dxi < 9; ++dxi) {
                    #pragma unroll
                    for (int px = 0; px < 4; ++px) {
                        acc[r3][dxi][px] = fmaf(fv[px], w[dxi + px], acc[r3][dxi][px]);
                    }
                }
            }
        }

        // write next 2 channels into the other buffer, one barrier
        if (more) {
            const int nb = (cur ^ 1) * (CPI * STILE);
            #pragma unroll
            for (int k = 0; k < STG; ++k)
                s_lds[nb + lidx[k]] = t[k];
        }
        __syncthreads();
        cur ^= 1;
    }

    // ---- epilogue: scale by 1/C and store 27 b128s
    const float scale = 1.0f / (float)CC;
    #pragma unroll
    for (int r3 = 0; r3 < 3; ++r3) {
        #pragma unroll
        for (int dxi = 0; dxi < 9; ++dxi) {
            const int d = (g * 3 + r3) * 9 + dxi;   // (dy+4)*9 + (dx+4)
            f4 o;
            o[0] = acc[r3][dxi][0] * scale;
            o[1] = acc[r3][dxi][1] * scale;
            o[2] = acc[r3][dxi][2] * scale;
            o[3] = acc[r3][dxi][3] * scale;
            *(f4*)(out + (long)(b * 81 + d) * HWS + y * WW + xg) = o;
        }
    }
}

extern "C" void kernel_launch(void* const* d_in, const int* in_sizes, int n_in,
                              void* d_out, int out_size, void* d_ws, size_t ws_size,
                              hipStream_t stream) {
    const float* first  = (const float*)d_in[0];
    const float* second = (const float*)d_in[1];
    float* out = (float*)d_out;

    dim3 grid(WW / TW, HH / TH, BB);   // (8, 8, 8) = 512 blocks, 2 per CU
    corr_kernel<<<grid, NTHR, 0, stream>>>(first, second, out);
}

// Round 4
// 363.681 us; speedup vs baseline: 1.1993x; 1.1993x over previous
//
#include <hip/hip_runtime.h>

// Problem constants (B=8, C=128, H=128, W=256, disp in [-4,4])
#define CC   128
#define HH   128
#define WW   256
#define BB   8
#define HWS  (HH * WW)        // 32768
#define TH   16               // tile rows per block
#define TW   16               // tile cols per block
#define SR   (TH + 8)         // 24 rows incl. halo
#define SC   (TW + 8)         // 24 cols incl. halo
#define ST   (SR * SC)        // 576 = exactly NTHR -> 1 staged elem/thread
#define NTHR 576              // 9 dy-waves x 64 lanes
#define NPAIR (CC / 2)        // 64 channel-pair iterations

typedef float    f4 __attribute__((ext_vector_type(4)));
typedef unsigned u4 __attribute__((ext_vector_type(4)));
typedef __fp16   h2 __attribute__((ext_vector_type(2)));   // matches cvt_pkrtz return

__global__ __launch_bounds__(NTHR, 5)
void corr_kernel(const float* __restrict__ first,
                 const float* __restrict__ second,
                 float* __restrict__ out)
{
    // second tile, channel-pairs packed as 2xf16 per u32, double-buffered: 4.6 KB
    __shared__ __align__(16) unsigned s_lds[2 * ST];

    const int tid = threadIdx.x;
    const int g   = tid >> 6;          // wave index = dy group 0..8 (dy = g-4)
    const int l   = tid & 63;
    const int r   = l >> 2;            // local row 0..15
    const int x0  = (l & 3) << 2;      // local col of pixel 0: 0,4,8,12

    const int bx = blockIdx.x * TW;
    const int by = blockIdx.y * TH;
    const int b  = blockIdx.z;

    const int y  = by + r;
    const int xg = bx + x0;

    // ---- staging: exactly one tile element per thread
    const int sr = tid / SC, sc = tid % SC;      // tid < 576 == ST
    const int ys = by - 4 + sr, xs = bx - 4 + sc;
    const bool v = ((unsigned)ys < HH) && ((unsigned)xs < WW);
    const float* sp = second + (long)b * CC * HWS + (v ? (ys * WW + xs) : 0);

    // ---- accumulators: 9 dx x 4 px (one dy per thread)
    float acc[9][4];
    #pragma unroll
    for (int d = 0; d < 9; ++d)
        #pragma unroll
        for (int q = 0; q < 4; ++q)
            acc[d][q] = 0.0f;

    // ---- prologue: pair 0 -> buf0; issue loads for pair 1
    float p1a, p1b;
    {
        float a0 = v ? sp[0]   : 0.0f;
        float b0 = v ? sp[HWS] : 0.0f;
        h2 pk = __builtin_amdgcn_cvt_pkrtz(a0, b0);
        s_lds[tid] = __builtin_bit_cast(unsigned, pk);
        p1a = v ? sp[2 * (long)HWS] : 0.0f;
        p1b = v ? sp[3 * (long)HWS] : 0.0f;
    }
    __syncthreads();

    const float* fp = first + (long)b * CC * HWS + (long)y * WW + xg;

    int cur = 0;
    for (int it = 0; it < NPAIR; ++it) {
        // far prefetch: issue loads for pair it+2 (2-iteration latency cover)
        float p2a = 0.0f, p2b = 0.0f;
        if (it + 2 < NPAIR) {
            const float* s2 = sp + (long)(2 * (it + 2)) * HWS;
            p2a = v ? s2[0]   : 0.0f;
            p2b = v ? s2[HWS] : 0.0f;
        }

        // ---- compute pair it from buf[cur]
        const unsigned* wrow = &s_lds[cur * ST + (r + g) * SC + x0];
        u4 wa = *(const u4*)wrow;
        u4 wb = *(const u4*)(wrow + 4);
        u4 wc = *(const u4*)(wrow + 8);
        unsigned wu[12] = { wa[0], wa[1], wa[2], wa[3],
                            wb[0], wb[1], wb[2], wb[3],
                            wc[0], wc[1], wc[2], wc[3] };
        float w0[12], w1[12];
        #pragma unroll
        for (int j = 0; j < 12; ++j) {
            h2 hv = __builtin_bit_cast(h2, wu[j]);
            w0[j] = (float)hv[0];
            w1[j] = (float)hv[1];
        }

        f4 f0 = *(const f4*)fp;          // first, channel 2*it (f32)
        f4 f1 = *(const f4*)(fp + HWS);  // first, channel 2*it+1
        fp += 2 * HWS;

        #pragma unroll
        for (int dxi = 0; dxi < 9; ++dxi) {
            #pragma unroll
            for (int px = 0; px < 4; ++px) {
                acc[dxi][px] = fmaf(f1[px], w1[dxi + px],
                               fmaf(f0[px], w0[dxi + px], acc[dxi][px]));
            }
        }

        // ---- write pair it+1 (loads issued one full iteration ago)
        if (it + 1 < NPAIR) {
            h2 pk = __builtin_amdgcn_cvt_pkrtz(p1a, p1b);
            s_lds[(cur ^ 1) * ST + tid] = __builtin_bit_cast(unsigned, pk);
        }
        __syncthreads();
        p1a = p2a; p1b = p2b;
        cur ^= 1;
    }

    // ---- epilogue: scale by 1/C, store 9 f4 rows
    const float scale = 1.0f / (float)CC;
    #pragma unroll
    for (int dxi = 0; dxi < 9; ++dxi) {
        f4 o;
        o[0] = acc[dxi][0] * scale;
        o[1] = acc[dxi][1] * scale;
        o[2] = acc[dxi][2] * scale;
        o[3] = acc[dxi][3] * scale;
        *(f4*)(out + ((long)(b * 81 + g * 9 + dxi)) * HWS + (long)y * WW + xg) = o;
    }
}

extern "C" void kernel_launch(void* const* d_in, const int* in_sizes, int n_in,
                              void* d_out, int out_size, void* d_ws, size_t ws_size,
                              hipStream_t stream) {
    const float* first  = (const float*)d_in[0];
    const float* second = (const float*)d_in[1];
    float* out = (float*)d_out;

    dim3 grid(WW / TW, HH / TH, BB);   // (16, 8, 8) = 1024 blocks
    corr_kernel<<<grid, NTHR, 0, stream>>>(first, second, out);
}

// Round 5
// 356.665 us; speedup vs baseline: 1.2229x; 1.0197x over previous
//
#include <hip/hip_runtime.h>

// B=8, C=128, H=128, W=256, disp in [-4,4]
#define CC   128
#define HH   128
#define WW   256
#define BB   8
#define HWS  (HH * WW)       // 32768
#define TH   16              // tile rows (per wave)
#define TWD  32              // tile cols (per wave: 4 groups x 8 px)
// wave units: 8 b x 8 yt x 8 xt x 9 dy = 4608; 1152 blocks x 4 waves
#define NBLK 1152

typedef float f4 __attribute__((ext_vector_type(4)));

__global__ __launch_bounds__(256, 4)
void corr_kernel(const float* __restrict__ first,
                 const float* __restrict__ second,
                 float* __restrict__ out)
{
    const int tid  = threadIdx.x;
    const int w_id = tid >> 6;
    const int l    = tid & 63;

    // XCD swizzle: 1152 = 8 * 144 -> XCD k handles batch k (halo stays in one L2)
    const int gsw  = (blockIdx.x & 7) * (NBLK / 8) + (blockIdx.x >> 3);
    const int u    = gsw * 4 + w_id;        // 0..4607
    const int dyi  = u % 9;                 // dy = dyi - 4
    const int rest = u / 9;                 // 0..511
    const int xt   = rest & 7;
    const int yt   = (rest >> 3) & 7;
    const int b    = rest >> 6;

    const int r   = l >> 2;                 // row 0..15
    const int xgi = l & 3;                  // x-group 0..3 (8 px each)

    const int y  = yt * TH + r;
    const int xg = xt * TWD + xgi * 8;

    const int  srow   = y + dyi - 4;
    const bool rowOK  = ((unsigned)srow < HH);
    const int  srow_c = min(max(srow, 0), HH - 1);

    const bool vA = (xg > 0);               // word A (cols xg-4..xg-1) in range?
    const bool vD = (xg < WW - 8);          // word D (cols xg+8..xg+11) in range?

    const long bbase = (long)b * CC * HWS;
    const float* fp  = first  + bbase + (long)y * WW + xg;
    const float* swB = second + bbase + (long)srow_c * WW + xg;       // words B,C
    const float* swA = swB + (vA ? -4 : 0);                            // clamped
    const float* swD = swB + (vD ?  8 : 0);                            // clamped

    float acc[9][8];
    #pragma unroll
    for (int d = 0; d < 9; ++d)
        #pragma unroll
        for (int q = 0; q < 8; ++q)
            acc[d][q] = 0.0f;

    const f4 zv = (f4)0.0f;

    #pragma unroll 2
    for (int c = 0; c < CC; ++c) {
        f4 wa = *(const f4*)swA;
        f4 wb = *(const f4*)swB;
        f4 wc = *(const f4*)(swB + 4);
        f4 wd = *(const f4*)swD;
        f4 f0 = *(const f4*)fp;
        f4 f1 = *(const f4*)(fp + 4);
        swA += HWS; swB += HWS; swD += HWS; fp += HWS;

        wa = vA ? wa : zv;                  // zero OOB halo words (per-lane cndmask)
        wd = vD ? wd : zv;

        float w[16] = { wa[0], wa[1], wa[2], wa[3],
                        wb[0], wb[1], wb[2], wb[3],
                        wc[0], wc[1], wc[2], wc[3],
                        wd[0], wd[1], wd[2], wd[3] };
        float f[8]  = { f0[0], f0[1], f0[2], f0[3],
                        f1[0], f1[1], f1[2], f1[3] };

        #pragma unroll
        for (int dxi = 0; dxi < 9; ++dxi) {
            #pragma unroll
            for (int px = 0; px < 8; ++px) {
                acc[dxi][px] = fmaf(f[px], w[dxi + px], acc[dxi][px]);
            }
        }
    }

    // epilogue: rows with OOB dy write zeros (scale_eff = 0)
    const float scale_eff = rowOK ? (1.0f / (float)CC) : 0.0f;
    float* op = out + ((long)(b * 81 + dyi * 9)) * HWS + (long)y * WW + xg;
    #pragma unroll
    for (int dxi = 0; dxi < 9; ++dxi) {
        f4 lo, hi;
        lo[0] = acc[dxi][0] * scale_eff;
        lo[1] = acc[dxi][1] * scale_eff;
        lo[2] = acc[dxi][2] * scale_eff;
        lo[3] = acc[dxi][3] * scale_eff;
        hi[0] = acc[dxi][4] * scale_eff;
        hi[1] = acc[dxi][5] * scale_eff;
        hi[2] = acc[dxi][6] * scale_eff;
        hi[3] = acc[dxi][7] * scale_eff;
        *(f4*)(op + (long)dxi * HWS)     = lo;
        *(f4*)(op + (long)dxi * HWS + 4) = hi;
    }
}

extern "C" void kernel_launch(void* const* d_in, const int* in_sizes, int n_in,
                              void* d_out, int out_size, void* d_ws, size_t ws_size,
                              hipStream_t stream) {
    const float* first  = (const float*)d_in[0];
    const float* second = (const float*)d_in[1];
    float* out = (float*)d_out;

    corr_kernel<<<dim3(NBLK), dim3(256), 0, stream>>>(first, second, out);
}

// Round 6
// 206.314 us; speedup vs baseline: 2.1141x; 1.7287x over previous
//
#include <hip/hip_runtime.h>

// B=8, C=128, H=128, W=256, disp in [-4,4]
#define CC   128
#define HH   128
#define WW   256
#define BB   8
#define HWS  (HH * WW)        // 32768
#define TH   16               // tile rows per block
#define TW   64               // tile cols per block
#define SROWS (TH + 8)        // 24
#define SCOLS (TW + 8)        // 72
#define STILE (SROWS * SCOLS) // 1728
#define NTHR 768              // 3 dy-groups x (16 rows x 16 x-chunks)

typedef float f4 __attribute__((ext_vector_type(4)));

__global__ __launch_bounds__(NTHR)
void corr_kernel(const float* __restrict__ first,
                 const float* __restrict__ second,
                 float* __restrict__ out)
{
    __shared__ float s_lds[2 * STILE];   // 13.8 KB double buffer

    const int tid = threadIdx.x;
    const int g   = tid >> 8;          // dy-group 0..2 (dy = 3g-4 .. 3g-2)
    const int p   = tid & 255;
    const int r   = p >> 4;            // local row 0..15
    const int xq  = p & 15;            // x-chunk 0..15
    const int x0  = xq << 2;

    const int bx = blockIdx.x * TW;
    const int by = blockIdx.y * TH;
    const int b  = blockIdx.z;

    const int y  = by + r;
    const int xg = bx + x0;

    // ---- staging map (verified in R1): 2-3 elements per thread
    const int i0 = tid;
    const int i1 = tid + NTHR;
    const int i2 = tid + 2 * NTHR;     // valid only if < STILE (tid < 192)

    const int sr0 = i0 / SCOLS, sc0 = i0 % SCOLS;
    const int sr1 = i1 / SCOLS, sc1 = i1 % SCOLS;
    const int sr2 = i2 / SCOLS, sc2 = i2 % SCOLS;

    const int ys0 = by - 4 + sr0, xs0 = bx - 4 + sc0;
    const int ys1 = by - 4 + sr1, xs1 = bx - 4 + sc1;
    const int ys2 = by - 4 + sr2, xs2 = bx - 4 + sc2;

    const bool v0 = ((unsigned)ys0 < HH) && ((unsigned)xs0 < WW);
    const bool v1 = ((unsigned)ys1 < HH) && ((unsigned)xs1 < WW);
    const bool v2 = (i2 < STILE) && ((unsigned)ys2 < HH) && ((unsigned)xs2 < WW);

    const float* sbase = second + (long)b * CC * HWS;
    const int go0 = v0 ? (ys0 * WW + xs0) : 0;
    const int go1 = v1 ? (ys1 * WW + xs1) : 0;
    const int go2 = v2 ? (ys2 * WW + xs2) : 0;

    float acc[3][9][4];
    #pragma unroll
    for (int a = 0; a < 3; ++a)
        #pragma unroll
        for (int d = 0; d < 9; ++d)
            #pragma unroll
            for (int q = 0; q < 4; ++q)
                acc[a][d][q] = 0.0f;

    // ---- prologue
    // stage(ch0) -> buf0 (one-time vmcnt(0) here is fine)
    {
        float a0 = v0 ? sbase[go0] : 0.0f;
        float a1 = v1 ? sbase[go1] : 0.0f;
        float a2 = v2 ? sbase[go2] : 0.0f;
        s_lds[i0] = a0;
        s_lds[i1] = a1;
        if (i2 < STILE) s_lds[i2] = a2;
    }
    // issue stage(ch1) into t1 regs and first(ch0) into fv — stay in flight
    float t1a = v0 ? sbase[HWS + go0] : 0.0f;
    float t1b = v1 ? sbase[HWS + go1] : 0.0f;
    float t1c = v2 ? sbase[HWS + go2] : 0.0f;

    const float* fptr = first + ((long)(b * CC) * HH + y) * WW + xg;
    f4 fv = *(const f4*)fptr;
    fptr += HWS;                       // -> ch1

    asm volatile("s_waitcnt lgkmcnt(0)" ::: "memory");
    __builtin_amdgcn_s_barrier();

    int cur = 0;
    #pragma unroll 2
    for (int it = 0; it < CC; ++it) {
        const bool more2 = (it + 2 < CC);

        // issue stage(it+2) loads (clamped channel; value unused for last 2 iters)
        const int c2 = more2 ? (it + 2) : it;
        const float* sb2 = sbase + (long)c2 * HWS;
        float t2a = v0 ? sb2[go0] : 0.0f;
        float t2b = v1 ? sb2[go1] : 0.0f;
        float t2c = v2 ? sb2[go2] : 0.0f;

        // issue first(it+1) load (pointer clamped in-bounds)
        f4 fnx = *(const f4*)fptr;
        fptr += more2 ? HWS : 0;

        // write stage(it+1) regs (issued last iter; compiler emits counted vmcnt)
        const int nb = (cur ^ 1) * STILE;
        s_lds[nb + i0] = t1a;
        s_lds[nb + i1] = t1b;
        if (i2 < STILE) s_lds[nb + i2] = t1c;

        // compute channel it from buf[cur] with fv (prefetched last iter)
        const float* sb_lds = &s_lds[cur * STILE];
        #pragma unroll
        for (int r3 = 0; r3 < 3; ++r3) {
            const int srow = r + g * 3 + r3;     // r + (dy+4)
            const f4* wp = (const f4*)&sb_lds[srow * SCOLS + x0];
            f4 wa = wp[0];
            f4 wb = wp[1];
            f4 wc = wp[2];
            float w[12] = { wa[0], wa[1], wa[2], wa[3],
                            wb[0], wb[1], wb[2], wb[3],
                            wc[0], wc[1], wc[2], wc[3] };
            #pragma unroll
            for (int dxi = 0; dxi < 9; ++dxi) {
                #pragma unroll
                for (int px = 0; px < 4; ++px) {
                    acc[r3][dxi][px] = fmaf(fv[px], w[dxi + px], acc[r3][dxi][px]);
                }
            }
        }

        // LDS-only drain + raw barrier: staging loads stay in flight across it
        asm volatile("s_waitcnt lgkmcnt(0)" ::: "memory");
        __builtin_amdgcn_s_barrier();

        t1a = t2a; t1b = t2b; t1c = t2c;
        fv = fnx;
        cur ^= 1;
    }

    // ---- epilogue: scale by 1/C, store 27 b128s
    const float scale = 1.0f / (float)CC;
    #pragma unroll
    for (int r3 = 0; r3 < 3; ++r3) {
        #pragma unroll
        for (int dxi = 0; dxi < 9; ++dxi) {
            const int d = (g * 3 + r3) * 9 + dxi;   // (dy+4)*9 + (dx+4)
            f4 o;
            o[0] = acc[r3][dxi][0] * scale;
            o[1] = acc[r3][dxi][1] * scale;
            o[2] = acc[r3][dxi][2] * scale;
            o[3] = acc[r3][dxi][3] * scale;
            *(f4*)(out + (long)(b * 81 + d) * HWS + y * WW + xg) = o;
        }
    }
}

extern "C" void kernel_launch(void* const* d_in, const int* in_sizes, int n_in,
                              void* d_out, int out_size, void* d_ws, size_t ws_size,
                              hipStream_t stream) {
    const float* first  = (const float*)d_in[0];
    const float* second = (const float*)d_in[1];
    float* out = (float*)d_out;

    dim3 grid(WW / TW, HH / TH, BB);   // (4, 8, 8) = 256 blocks, 1 per CU
    corr_kernel<<<grid, NTHR, 0, stream>>>(first, second, out);
}

// Round 8
// 180.289 us; speedup vs baseline: 2.4193x; 1.1444x over previous
//
#include <hip/hip_runtime.h>

// B=8, C=128, H=128, W=256, disp in [-4,4]
// R1-verified skeleton + channel-pair f16 LDS packing (R4-verified primitives).
#define CC   128
#define HH   128
#define WW   256
#define BB   8
#define HWS  (HH * WW)        // 32768
#define TH   16               // tile rows per block
#define TW   64               // tile cols per block
#define SROWS (TH + 8)        // 24
#define SCOLS (TW + 8)        // 72
#define STILE (SROWS * SCOLS) // 1728 u32 (each u32 = 2 f16 = channel pair)
#define NTHR 768              // 3 dy-groups x (16 rows x 16 x-chunks)
#define NPER (CC / 2)         // 64 channel-pair iterations

typedef float    f4  __attribute__((ext_vector_type(4)));
typedef unsigned u4v __attribute__((ext_vector_type(4)));
typedef __fp16   h2  __attribute__((ext_vector_type(2)));   // cvt_pkrtz return type

static __device__ __forceinline__ unsigned pack2(float a, float b) {
    h2 pk = __builtin_amdgcn_cvt_pkrtz(a, b);   // R4-verified: lo=a, hi=b
    return __builtin_bit_cast(unsigned, pk);
}

__global__ __launch_bounds__(NTHR, 3)
void corr_kernel(const float* __restrict__ first,
                 const float* __restrict__ second,
                 float* __restrict__ out)
{
    __shared__ __align__(16) unsigned s_lds[2 * STILE];   // 13.8 KB double buffer

    const int tid = threadIdx.x;
    const int g   = tid >> 8;          // dy-group 0..2 (dy = 3g-4 .. 3g-2)
    const int p   = tid & 255;
    const int r   = p >> 4;            // local row 0..15
    const int xq  = p & 15;            // x-chunk 0..15
    const int x0  = xq << 2;

    const int bx = blockIdx.x * TW;
    const int by = blockIdx.y * TH;
    const int b  = blockIdx.z;

    const int y  = by + r;
    const int xg = bx + x0;

    // ---- staging map (R1-verified): 2-3 u32 positions per thread
    const int i0 = tid;
    const int i1 = tid + NTHR;
    const int i2 = tid + 2 * NTHR;     // valid only if < STILE (tid < 192)

    const int sr0 = i0 / SCOLS, sc0 = i0 % SCOLS;
    const int sr1 = i1 / SCOLS, sc1 = i1 % SCOLS;
    const int sr2 = i2 / SCOLS, sc2 = i2 % SCOLS;

    const int ys0 = by - 4 + sr0, xs0 = bx - 4 + sc0;
    const int ys1 = by - 4 + sr1, xs1 = bx - 4 + sc1;
    const int ys2 = by - 4 + sr2, xs2 = bx - 4 + sc2;

    const bool v0 = ((unsigned)ys0 < HH) && ((unsigned)xs0 < WW);
    const bool v1 = ((unsigned)ys1 < HH) && ((unsigned)xs1 < WW);
    const bool v2 = (i2 < STILE) && ((unsigned)ys2 < HH) && ((unsigned)xs2 < WW);

    const float* sbase = second + (long)b * CC * HWS;
    const int go0 = v0 ? (ys0 * WW + xs0) : 0;
    const int go1 = v1 ? (ys1 * WW + xs1) : 0;
    const int go2 = v2 ? (ys2 * WW + xs2) : 0;

    float acc[3][9][4];
    #pragma unroll
    for (int a = 0; a < 3; ++a)
        #pragma unroll
        for (int d = 0; d < 9; ++d)
            #pragma unroll
            for (int q = 0; q < 4; ++q)
                acc[a][d][q] = 0.0f;

    // ---- prologue: stage pair 0 (channels 0,1) into buf0
    {
        float a0 = v0 ? sbase[go0] : 0.0f, b0 = v0 ? sbase[go0 + HWS] : 0.0f;
        float a1 = v1 ? sbase[go1] : 0.0f, b1 = v1 ? sbase[go1 + HWS] : 0.0f;
        float a2 = v2 ? sbase[go2] : 0.0f, b2 = v2 ? sbase[go2 + HWS] : 0.0f;
        s_lds[i0] = pack2(a0, b0);
        s_lds[i1] = pack2(a1, b1);
        if (i2 < STILE) s_lds[i2] = pack2(a2, b2);
    }
    __syncthreads();

    const float* fptr = first + ((long)(b * CC) * HH + y) * WW + xg;

    int cur = 0;
    for (int it = 0; it < NPER; ++it) {
        // issue-early: next pair's staging loads (written at bottom this iter)
        const int ip = (it + 1 < NPER) ? (it + 1) : it;
        const float* sb = sbase + (long)(2 * ip) * HWS;
        float t0a = v0 ? sb[go0] : 0.0f, t0b = v0 ? sb[go0 + HWS] : 0.0f;
        float t1a = v1 ? sb[go1] : 0.0f, t1b = v1 ? sb[go1 + HWS] : 0.0f;
        float t2a = v2 ? sb[go2] : 0.0f, t2b = v2 ? sb[go2 + HWS] : 0.0f;

        // first: channels 2it, 2it+1 (f32, coalesced b128)
        const float* fpit = fptr + (long)(2 * it) * HWS;
        f4 f0 = *(const f4*)fpit;
        f4 f1 = *(const f4*)(fpit + HWS);

        // compute both channels from buf[cur]
        const unsigned* sb_lds = &s_lds[cur * STILE];
        #pragma unroll
        for (int r3 = 0; r3 < 3; ++r3) {
            const int srow = r + g * 3 + r3;     // r + (dy+4), R1-verified
            const u4v* wp = (const u4v*)&sb_lds[srow * SCOLS + x0];
            u4v qa = wp[0];
            u4v qb = wp[1];
            u4v qc = wp[2];
            unsigned wu[12] = { qa[0], qa[1], qa[2], qa[3],
                                qb[0], qb[1], qb[2], qb[3],
                                qc[0], qc[1], qc[2], qc[3] };
            float wlo[12], whi[12];
            #pragma unroll
            for (int j = 0; j < 12; ++j) {
                h2 hv = __builtin_bit_cast(h2, wu[j]);   // R4-verified unpack
                wlo[j] = (float)hv[0];
                whi[j] = (float)hv[1];
            }
            #pragma unroll
            for (int dxi = 0; dxi < 9; ++dxi) {
                #pragma unroll
                for (int px = 0; px < 4; ++px) {
                    acc[r3][dxi][px] = fmaf(f1[px], whi[dxi + px],
                                       fmaf(f0[px], wlo[dxi + px],
                                            acc[r3][dxi][px]));
                }
            }
        }

        // write pair it+1 into other buffer, single barrier (R1-verified timing)
        if (it + 1 < NPER) {
            const int nb = (cur ^ 1) * STILE;
            s_lds[nb + i0] = pack2(t0a, t0b);
            s_lds[nb + i1] = pack2(t1a, t1b);
            if (i2 < STILE) s_lds[nb + i2] = pack2(t2a, t2b);
        }
        __syncthreads();
        cur ^= 1;
    }

    // ---- epilogue: scale by 1/C, store 27 b128s (R1-verified)
    const float scale = 1.0f / (float)CC;
    #pragma unroll
    for (int r3 = 0; r3 < 3; ++r3) {
        #pragma unroll
        for (int dxi = 0; dxi < 9; ++dxi) {
            const int d = (g * 3 + r3) * 9 + dxi;   // (dy+4)*9 + (dx+4)
            f4 o;
            o[0] = acc[r3][dxi][0] * scale;
            o[1] = acc[r3][dxi][1] * scale;
            o[2] = acc[r3][dxi][2] * scale;
            o[3] = acc[r3][dxi][3] * scale;
            *(f4*)(out + (long)(b * 81 + d) * HWS + y * WW + xg) = o;
        }
    }
}

extern "C" void kernel_launch(void* const* d_in, const int* in_sizes, int n_in,
                              void* d_out, int out_size, void* d_ws, size_t ws_size,
                              hipStream_t stream) {
    const float* first  = (const float*)d_in[0];
    const float* second = (const float*)d_in[1];
    float* out = (float*)d_out;

    dim3 grid(WW / TW, HH / TH, BB);   // (4, 8, 8) = 256 blocks, 1 per CU
    corr_kernel<<<grid, NTHR, 0, stream>>>(first, second, out);
}